// Round 1
// baseline (322.926 us; speedup 1.0000x reference)
//
#include <hip/hip_runtime.h>

// entmax-1.5 over rows of an 8192 x 4096 fp32 matrix, boolean mask.
// Strategy: one wave per row; 64 fp32 elements per lane live in VGPRs.
// tau found by 26-step bisection on f(tau) = sum(relu(z - tau)^2) - 1,
// bracketed in [max(z)-1, max(z)] (max element contributes exactly 1 at lo).
// All reductions are wave-level shfl_xor butterflies: no LDS, no barriers.

constexpr int NROWS = 8192;
constexpr int NCOL  = 4096;
constexpr int EPL   = 64;   // elements per lane (4096 / 64 lanes)
constexpr int CHUNK = 16;   // float4 chunks per lane
constexpr int NITER = 26;   // bisection steps: bracket width 1 -> 2^-26 ~ 1.5e-8

__global__ __launch_bounds__(256, 4)
void entmax15_kernel(const float* __restrict__ scores,
                     const int*   __restrict__ mask,
                     float*       __restrict__ out)
{
    const int lane = threadIdx.x & 63;
    const int wave = threadIdx.x >> 6;          // 4 waves per block = 4 rows
    const int row  = (blockIdx.x << 2) | wave;  // grid = 2048 -> rows 0..8191

    const float* srow = scores + (size_t)row * NCOL;
    const int*   mrow = mask   + (size_t)row * NCOL;
    float*       orow = out    + (size_t)row * NCOL;

    float z[EPL];

    // Coalesced float4/int4 loads: chunk c covers columns [c*256, c*256+256),
    // lane takes 4 consecutive elements at c*256 + lane*4 (16B aligned).
    #pragma unroll
    for (int c = 0; c < CHUNK; ++c) {
        const int base = c * 256 + lane * 4;
        const float4 s4 = *reinterpret_cast<const float4*>(srow + base);
        const int4   m4 = *reinterpret_cast<const int4*>(mrow + base);
        // reference: where(mask, s, -1e4) / 2
        z[c * 4 + 0] = m4.x ? s4.x * 0.5f : -5000.0f;
        z[c * 4 + 1] = m4.y ? s4.y * 0.5f : -5000.0f;
        z[c * 4 + 2] = m4.z ? s4.z * 0.5f : -5000.0f;
        z[c * 4 + 3] = m4.w ? s4.w * 0.5f : -5000.0f;
    }

    // Row max: per-lane tree then 6-step wave butterfly (result in all lanes).
    float mx = z[0];
    #pragma unroll
    for (int i = 1; i < EPL; ++i) mx = fmaxf(mx, z[i]);
    #pragma unroll
    for (int off = 1; off < 64; off <<= 1)
        mx = fmaxf(mx, __shfl_xor(mx, off, 64));

    #pragma unroll
    for (int i = 0; i < EPL; ++i) z[i] -= mx;   // now z <= 0, max elem == 0

    // Bisection: f(-1) >= 1 (max elem gives (0+1)^2 = 1), f(0) = 0.
    float lo = -1.0f, hi = 0.0f;
    for (int it = 0; it < NITER; ++it) {
        const float t = 0.5f * (lo + hi);
        // 4 independent accumulators to break the FMA dependence chain.
        float s0 = 0.f, s1 = 0.f, s2 = 0.f, s3 = 0.f;
        #pragma unroll
        for (int i = 0; i < EPL; i += 4) {
            const float d0 = fmaxf(z[i + 0] - t, 0.f);
            const float d1 = fmaxf(z[i + 1] - t, 0.f);
            const float d2 = fmaxf(z[i + 2] - t, 0.f);
            const float d3 = fmaxf(z[i + 3] - t, 0.f);
            s0 = fmaf(d0, d0, s0);
            s1 = fmaf(d1, d1, s1);
            s2 = fmaf(d2, d2, s2);
            s3 = fmaf(d3, d3, s3);
        }
        float s = (s0 + s1) + (s2 + s3);
        #pragma unroll
        for (int off = 1; off < 64; off <<= 1)
            s += __shfl_xor(s, off, 64);
        if (s >= 1.0f) lo = t; else hi = t;     // wave-uniform branch
    }
    const float tau = 0.5f * (lo + hi);

    // Epilogue: p = relu(z - tau)^2, coalesced float4 stores.
    #pragma unroll
    for (int c = 0; c < CHUNK; ++c) {
        const int base = c * 256 + lane * 4;
        float4 o;
        float d;
        d = fmaxf(z[c * 4 + 0] - tau, 0.f); o.x = d * d;
        d = fmaxf(z[c * 4 + 1] - tau, 0.f); o.y = d * d;
        d = fmaxf(z[c * 4 + 2] - tau, 0.f); o.z = d * d;
        d = fmaxf(z[c * 4 + 3] - tau, 0.f); o.w = d * d;
        *reinterpret_cast<float4*>(orow + base) = o;
    }
}

extern "C" void kernel_launch(void* const* d_in, const int* in_sizes, int n_in,
                              void* d_out, int out_size, void* d_ws, size_t ws_size,
                              hipStream_t stream)
{
    const float* scores = (const float*)d_in[0];
    const int*   mask   = (const int*)d_in[1];
    float*       out    = (float*)d_out;

    dim3 grid(NROWS / 4);   // 4 rows (waves) per 256-thread block
    dim3 block(256);
    hipLaunchKernelGGL(entmax15_kernel, grid, block, 0, stream,
                       scores, mask, out);
}

// Round 2
// 311.669 us; speedup vs baseline: 1.0361x; 1.0361x over previous
//
#include <hip/hip_runtime.h>

// entmax-1.5 over rows of an 8192 x 4096 fp32 matrix, boolean mask (int32).
// One wave per row; 64 fp32 elements per lane in VGPRs.
// tau* solves g(tau) = sum(relu(z - tau)^2) - 1 = 0. g is convex, decreasing,
// piecewise-quadratic; |g'(tau*)| >= 2, so Newton from tau0 = max(z) - 1
// converges monotonically from the left. 8 fixed iterations -> ~fp32 exact.
// launch_bounds(256,2): allow up to 256 arch VGPRs so z[64] is NOT shuffled
// through AGPRs (R1: VGPR_Count=64 + 49% VALUBusy showed accvgpr spill copies).

constexpr int NROWS = 8192;
constexpr int NCOL  = 4096;
constexpr int EPL   = 64;   // elements per lane (4096 / 64 lanes)
constexpr int CHUNK = 16;   // float4 chunks per lane
constexpr int NITER = 8;    // Newton steps (quadratic convergence, |g'|>=2)

__global__ __launch_bounds__(256, 2)
void entmax15_kernel(const float* __restrict__ scores,
                     const int*   __restrict__ mask,
                     float*       __restrict__ out)
{
    const int lane = threadIdx.x & 63;
    const int wave = threadIdx.x >> 6;          // 4 waves per block = 4 rows
    const int row  = (blockIdx.x << 2) | wave;  // grid = 2048 -> rows 0..8191

    const float* srow = scores + (size_t)row * NCOL;
    const int*   mrow = mask   + (size_t)row * NCOL;
    float*       orow = out    + (size_t)row * NCOL;

    float z[EPL];

    // Coalesced float4/int4 loads: chunk c covers columns [c*256, c*256+256),
    // lane takes 4 consecutive elements at c*256 + lane*4 (16B aligned).
    #pragma unroll
    for (int c = 0; c < CHUNK; ++c) {
        const int base = c * 256 + lane * 4;
        const float4 s4 = *reinterpret_cast<const float4*>(srow + base);
        const int4   m4 = *reinterpret_cast<const int4*>(mrow + base);
        // reference: where(mask, s, -1e4) / 2  (shift folded into tau0)
        z[c * 4 + 0] = m4.x ? s4.x * 0.5f : -5000.0f;
        z[c * 4 + 1] = m4.y ? s4.y * 0.5f : -5000.0f;
        z[c * 4 + 2] = m4.z ? s4.z * 0.5f : -5000.0f;
        z[c * 4 + 3] = m4.w ? s4.w * 0.5f : -5000.0f;
    }

    // Row max: per-lane tree then 6-step wave butterfly (result in all lanes).
    float mx = z[0];
    #pragma unroll
    for (int i = 1; i < EPL; ++i) mx = fmaxf(mx, z[i]);
    #pragma unroll
    for (int off = 1; off < 64; off <<= 1)
        mx = fmaxf(mx, __shfl_xor(mx, off, 64));

    // Newton from the left: tau* in [mx-1, mx]; g(mx-1) >= 0.
    // At any t <= tau*: sum(relu(z-t)) >= sum(sqrt(p_i)) >= 1, so the
    // denominator is always >= 1 (never divide by ~0).
    float t = mx - 1.0f;
    for (int it = 0; it < NITER; ++it) {
        float s2a = 0.f, s2b = 0.f, s2c = 0.f, s2d = 0.f;  // sum d^2
        float s1a = 0.f, s1b = 0.f, s1c = 0.f, s1d = 0.f;  // sum d
        #pragma unroll
        for (int i = 0; i < EPL; i += 4) {
            const float d0 = fmaxf(z[i + 0] - t, 0.f);
            const float d1 = fmaxf(z[i + 1] - t, 0.f);
            const float d2 = fmaxf(z[i + 2] - t, 0.f);
            const float d3 = fmaxf(z[i + 3] - t, 0.f);
            s2a = fmaf(d0, d0, s2a);  s1a += d0;
            s2b = fmaf(d1, d1, s2b);  s1b += d1;
            s2c = fmaf(d2, d2, s2c);  s1c += d2;
            s2d = fmaf(d3, d3, s2d);  s1d += d3;
        }
        float s2 = (s2a + s2b) + (s2c + s2d);
        float s1 = (s1a + s1b) + (s1c + s1d);
        #pragma unroll
        for (int off = 1; off < 64; off <<= 1) {
            s2 += __shfl_xor(s2, off, 64);
            s1 += __shfl_xor(s1, off, 64);
        }
        // t_{n+1} = t - g/g' = t + (s2 - 1) / (2*s1); wave-uniform.
        t = t + (s2 - 1.0f) / (2.0f * s1);
    }

    // Epilogue: p = relu(z - tau)^2, coalesced float4 stores.
    #pragma unroll
    for (int c = 0; c < CHUNK; ++c) {
        const int base = c * 256 + lane * 4;
        float4 o;
        float d;
        d = fmaxf(z[c * 4 + 0] - t, 0.f); o.x = d * d;
        d = fmaxf(z[c * 4 + 1] - t, 0.f); o.y = d * d;
        d = fmaxf(z[c * 4 + 2] - t, 0.f); o.z = d * d;
        d = fmaxf(z[c * 4 + 3] - t, 0.f); o.w = d * d;
        *reinterpret_cast<float4*>(orow + base) = o;
    }
}

extern "C" void kernel_launch(void* const* d_in, const int* in_sizes, int n_in,
                              void* d_out, int out_size, void* d_ws, size_t ws_size,
                              hipStream_t stream)
{
    const float* scores = (const float*)d_in[0];
    const int*   mask   = (const int*)d_in[1];
    float*       out    = (float*)d_out;

    dim3 grid(NROWS / 4);   // 4 rows (waves) per 256-thread block
    dim3 block(256);
    hipLaunchKernelGGL(entmax15_kernel, grid, block, 0, stream,
                       scores, mask, out);
}